// Round 7
// baseline (375.138 us; speedup 1.0000x reference)
//
#include <hip/hip_runtime.h>
#include <hip/hip_bf16.h>
#include <math.h>

#define N_NODES 50000
#define N_EDGES 800000
#define IN_DIM 32
#define HIDDEN 64
#define Z_DIM 32
#define SCAN_B 256
#define NB_SCAN ((N_NODES + SCAN_B - 1) / SCAN_B)   // 196

// bf16 (stored as ushort) <-> f32 helpers, RNE
__device__ __forceinline__ float bf2f(unsigned short u) {
    return __uint_as_float(((unsigned int)u) << 16);
}
__device__ __forceinline__ unsigned short f2bf(float f) {
    unsigned int u = __float_as_uint(f);
    u += 0x7fffu + ((u >> 16) & 1u);
    return (unsigned short)(u >> 16);
}

// ---------------------------------------------------------------------------
// prep: convert x to bf16, zero degree counters, detect edge_index dtype.
__global__ void prep_kernel(const float* __restrict__ x, unsigned short* __restrict__ xb,
                            const int* __restrict__ raw, int* __restrict__ flag,
                            int* __restrict__ cnt) {
    int i = blockIdx.x * 256 + threadIdx.x;
    if (i < N_NODES * IN_DIM) xb[i] = f2bf(x[i]);
    if (i < N_NODES) cnt[i] = 0;
    if (blockIdx.x == 0 && threadIdx.x < 64) {
        int odd = raw[2 * threadIdx.x + 1];
        unsigned long long b = __ballot(odd != 0);
        if (threadIdx.x == 0) *flag = (b == 0ULL) ? 1 : 0;
    }
}

// degree histogram straight off the raw edge_index (uniform branch on dtype)
__global__ void hist_kernel(const void* __restrict__ raw, const int* __restrict__ flag,
                            int* __restrict__ cnt) {
    int e = blockIdx.x * 256 + threadIdx.x;
    if (e >= N_EDGES) return;
    int d = (*flag) ? (int)((const long long*)raw)[N_EDGES + e]
                    : ((const int*)raw)[N_EDGES + e];
    atomicAdd(&cnt[d], 1);
}

// ---------------------------------------------------------------------------
// 3-phase exclusive scan over cnt -> rowptr; also dinv = rsqrt(deg+1).
__global__ void scan1_kernel(const int* __restrict__ cnt, int* __restrict__ pre,
                             int* __restrict__ bsum, float* __restrict__ dinv) {
    __shared__ int s[SCAN_B];
    int t = threadIdx.x;
    int g = blockIdx.x * SCAN_B + t;
    int v = (g < N_NODES) ? cnt[g] : 0;
    if (g < N_NODES) dinv[g] = rsqrtf((float)(v + 1));   // +1 self loop
    s[t] = v;
    __syncthreads();
    for (int o = 1; o < SCAN_B; o <<= 1) {
        int add = (t >= o) ? s[t - o] : 0;
        __syncthreads();
        s[t] += add;
        __syncthreads();
    }
    if (g < N_NODES) pre[g] = s[t] - v;
    if (t == SCAN_B - 1) bsum[blockIdx.x] = s[t];
}

__global__ void scan2_kernel(int* __restrict__ bsum, int nb) {   // single block
    __shared__ int s[256];
    int t = threadIdx.x;
    int v = (t < nb) ? bsum[t] : 0;
    s[t] = v;
    __syncthreads();
    for (int o = 1; o < 256; o <<= 1) {
        int add = (t >= o) ? s[t - o] : 0;
        __syncthreads();
        s[t] += add;
        __syncthreads();
    }
    if (t < nb) bsum[t] = s[t] - v;
}

__global__ void scan3_kernel(int* __restrict__ rowptr, const int* __restrict__ bsum,
                             int* __restrict__ cursor) {
    int g = blockIdx.x * SCAN_B + threadIdx.x;
    if (g < N_NODES) {
        int r = rowptr[g] + bsum[blockIdx.x];
        rowptr[g] = r;
        cursor[g] = r;
    }
    if (g == 0) rowptr[N_NODES] = N_EDGES;
}

// counting-sort scatter; emits packed (src, dinv[src]) per edge.
__global__ void scatter_kernel(const void* __restrict__ raw, const int* __restrict__ flag,
                               const float* __restrict__ dinv,
                               int* __restrict__ cursor, int2* __restrict__ ep) {
    int e = blockIdx.x * 256 + threadIdx.x;
    if (e >= N_EDGES) return;
    int s, d;
    if (*flag) {
        s = (int)((const long long*)raw)[e];
        d = (int)((const long long*)raw)[N_EDGES + e];
    } else {
        s = ((const int*)raw)[e];
        d = ((const int*)raw)[N_EDGES + e];
    }
    int p = atomicAdd(&cursor[d], 1);
    ep[p] = make_int2(s, __float_as_int(dinv[s]));
}

// ---------------------------------------------------------------------------
// Two-node interleaved wave-cooperative aggregation over a bf16 table.
// Issues VMEM for node A and node B before consuming either -> 2 concurrent
// latency chains per wave, 2-way ILP in reduce.
// Outputs srowA/srowB distributed lane==k (valid for lane < DIN).
template<int DIN, int U>
__device__ __forceinline__ void agg_row2_bf(int va, int vb, bool hasB,
                                            const int* __restrict__ rowptr,
                                            const int2* __restrict__ ep,
                                            const float* __restrict__ dinv,
                                            const unsigned short* __restrict__ h,
                                            float& srowA, float& srowB) {
    const int LPR  = DIN / 8;          // lanes per row: 8 (D=64) / 4 (D=32)
    const int EPB  = 64 / LPR;         // rows per batch: 8 / 16
    const int STEP = EPB * U;
    int lane = threadIdx.x & 63;
    int q    = lane & (LPR - 1);
    int sub  = lane / LPR;
    int a0 = rowptr[va], a1 = rowptr[va + 1];
    int b0 = 0, b1 = 0;
    if (hasB) { b0 = rowptr[vb]; b1 = rowptr[vb + 1]; }
    float accA[8], accB[8];
#pragma unroll
    for (int j = 0; j < 8; j++) { accA[j] = 0.0f; accB[j] = 0.0f; }
    int ea = a0, eb = b0;
    while (ea < a1 || eb < b1) {
        int2  prA[U], prB[U];
        uint4 rvA[U], rvB[U];
        float wA[U], wB[U];
#pragma unroll
        for (int u = 0; u < U; u++) {          // ep pair loads, both nodes
            int eeA = ea + u * EPB + sub;
            int eeB = eb + u * EPB + sub;
            prA[u] = ep[(eeA < N_EDGES) ? eeA : (N_EDGES - 1)];
            prB[u] = ep[(eeB < N_EDGES) ? eeB : (N_EDGES - 1)];
        }
#pragma unroll
        for (int u = 0; u < U; u++) {          // row loads, both nodes
            int eeA = ea + u * EPB + sub;
            int eeB = eb + u * EPB + sub;
            wA[u]  = (eeA < a1) ? __int_as_float(prA[u].y) : 0.0f;
            wB[u]  = (eeB < b1) ? __int_as_float(prB[u].y) : 0.0f;
            rvA[u] = ((const uint4*)(h + (size_t)prA[u].x * DIN))[q];
            rvB[u] = ((const uint4*)(h + (size_t)prB[u].x * DIN))[q];
        }
#pragma unroll
        for (int u = 0; u < U; u++) {
            unsigned int a0w = rvA[u].x, a1w = rvA[u].y, a2w = rvA[u].z, a3w = rvA[u].w;
            unsigned int b0w = rvB[u].x, b1w = rvB[u].y, b2w = rvB[u].z, b3w = rvB[u].w;
            accA[0] = fmaf(wA[u], __uint_as_float(a0w << 16),         accA[0]);
            accB[0] = fmaf(wB[u], __uint_as_float(b0w << 16),         accB[0]);
            accA[1] = fmaf(wA[u], __uint_as_float(a0w & 0xffff0000u), accA[1]);
            accB[1] = fmaf(wB[u], __uint_as_float(b0w & 0xffff0000u), accB[1]);
            accA[2] = fmaf(wA[u], __uint_as_float(a1w << 16),         accA[2]);
            accB[2] = fmaf(wB[u], __uint_as_float(b1w << 16),         accB[2]);
            accA[3] = fmaf(wA[u], __uint_as_float(a1w & 0xffff0000u), accA[3]);
            accB[3] = fmaf(wB[u], __uint_as_float(b1w & 0xffff0000u), accB[3]);
            accA[4] = fmaf(wA[u], __uint_as_float(a2w << 16),         accA[4]);
            accB[4] = fmaf(wB[u], __uint_as_float(b2w << 16),         accB[4]);
            accA[5] = fmaf(wA[u], __uint_as_float(a2w & 0xffff0000u), accA[5]);
            accB[5] = fmaf(wB[u], __uint_as_float(b2w & 0xffff0000u), accB[5]);
            accA[6] = fmaf(wA[u], __uint_as_float(a3w << 16),         accA[6]);
            accB[6] = fmaf(wB[u], __uint_as_float(b3w << 16),         accB[6]);
            accA[7] = fmaf(wA[u], __uint_as_float(a3w & 0xffff0000u), accA[7]);
            accB[7] = fmaf(wB[u], __uint_as_float(b3w & 0xffff0000u), accB[7]);
        }
        ea += STEP;
        eb += STEP;
    }
#pragma unroll
    for (int o = LPR; o < 64; o <<= 1) {
#pragma unroll
        for (int j = 0; j < 8; j++) {
            accA[j] += __shfl_xor(accA[j], o);
            accB[j] += __shfl_xor(accB[j], o);
        }
    }
    // lane k wants element (k&7) held at source lane k>>3
    int srcl = lane >> 3;
    int c = lane & 7;
    float tA[8], tB[8];
#pragma unroll
    for (int j = 0; j < 8; j++) {
        tA[j] = __shfl(accA[j], srcl);
        tB[j] = __shfl(accB[j], srcl);
    }
    float gA = (c < 4) ? ((c < 2) ? (c == 0 ? tA[0] : tA[1]) : (c == 2 ? tA[2] : tA[3]))
                       : ((c < 6) ? (c == 4 ? tA[4] : tA[5]) : (c == 6 ? tA[6] : tA[7]));
    float gB = (c < 4) ? ((c < 2) ? (c == 0 ? tB[0] : tB[1]) : (c == 2 ? tB[2] : tB[3]))
                       : ((c < 6) ? (c == 4 ? tB[4] : tB[5]) : (c == 6 ? tB[6] : tB[7]));
    int hidx = (lane < DIN) ? lane : 0;
    float dvA = dinv[va];
    float hkA = bf2f(h[(size_t)va * DIN + hidx]);
    srowA = dvA * fmaf(dvA, hkA, gA);
    if (hasB) {
        float dvB = dinv[vb];
        float hkB = bf2f(h[(size_t)vb * DIN + hidx]);
        srowB = dvB * fmaf(dvB, hkB, gB);
    } else {
        srowB = 0.0f;
    }
}

// ---------------------------------------------------------------------------
// Fused layer: out[v][lane] = relu( (A h)[v][:] @ W[DIN,64] + b ), bf16 out.
// Two nodes per wave per trip; GEMM interleaved for 2-way FMA ILP.
template<int DIN>
__global__ __launch_bounds__(256) void fused_layer_kernel(
        const int* __restrict__ rowptr, const int2* __restrict__ ep,
        const float* __restrict__ dinv, const unsigned short* __restrict__ h,
        const float* __restrict__ W, const float* __restrict__ b,
        unsigned short* __restrict__ out) {
    __shared__ float sW[DIN * 64];
    for (int i = threadIdx.x; i < DIN * 64; i += 256) sW[i] = W[i];
    __syncthreads();
    int lane = threadIdx.x & 63;
    float bb = b[lane];
    int wid = (blockIdx.x * blockDim.x + threadIdx.x) >> 6;
    int nw  = (gridDim.x * blockDim.x) >> 6;
    const int U = (DIN == 64) ? 2 : 1;             // STEP = 16 rows either way
    for (int va = wid; va < N_NODES; va += 2 * nw) {
        int vb = va + nw;
        bool hasB = vb < N_NODES;
        float srowA, srowB;
        agg_row2_bf<DIN, U>(va, vb, hasB, rowptr, ep, dinv, h, srowA, srowB);
        float aA = bb, aB = bb;
#pragma unroll
        for (int k = 0; k < DIN; k++) {
            float wk = sW[k * 64 + lane];
            aA = fmaf(__shfl(srowA, k), wk, aA);
            aB = fmaf(__shfl(srowB, k), wk, aB);
        }
        out[(size_t)va * 64 + lane] = f2bf(fmaxf(aA, 0.0f));
        if (hasB) out[(size_t)vb * 64 + lane] = f2bf(fmaxf(aB, 0.0f));
    }
}

// Fused heads: a2 = (A h2)[v]; lanes<32 -> mu col, lanes>=32 -> lv col;
// z = mu + exp(0.5 lv)*eps. d_out = [z | mu | lv], fp32. Two nodes per trip.
__global__ __launch_bounds__(256) void fused_head_kernel(
        const int* __restrict__ rowptr, const int2* __restrict__ ep,
        const float* __restrict__ dinv, const unsigned short* __restrict__ h,
        const float* __restrict__ Wmu, const float* __restrict__ bmu,
        const float* __restrict__ Wlv, const float* __restrict__ blv,
        const float* __restrict__ eps, float* __restrict__ outz) {
    __shared__ float sW[64 * 64];                  // [k][0:32]=Wmu, [k][32:64]=Wlv
    for (int i = threadIdx.x; i < 64 * 64; i += 256) {
        int k = i >> 6, c = i & 63;
        sW[i] = (c < 32) ? Wmu[k * 32 + c] : Wlv[k * 32 + (c - 32)];
    }
    __syncthreads();
    int lane = threadIdx.x & 63;
    int f = lane & 31;
    bool hi = lane >= 32;
    float bb = hi ? blv[f] : bmu[f];
    float* z  = outz;
    float* mu = outz + (size_t)N_NODES * Z_DIM;
    float* lv = outz + 2 * (size_t)N_NODES * Z_DIM;
    int wid = (blockIdx.x * blockDim.x + threadIdx.x) >> 6;
    int nw  = (gridDim.x * blockDim.x) >> 6;
    for (int va = wid; va < N_NODES; va += 2 * nw) {
        int vb = va + nw;
        bool hasB = vb < N_NODES;
        float srowA, srowB;
        agg_row2_bf<64, 2>(va, vb, hasB, rowptr, ep, dinv, h, srowA, srowB);
        float aA = bb, aB = bb;
#pragma unroll
        for (int k = 0; k < 64; k++) {
            float wk = sW[k * 64 + lane];
            aA = fmaf(__shfl(srowA, k), wk, aA);
            aB = fmaf(__shfl(srowB, k), wk, aB);
        }
        {   // node A epilogue
            float t = expf(0.5f * aA) * eps[(size_t)va * Z_DIM + f];
            float tlo = __shfl(t, lane | 32);
            size_t o = (size_t)va * Z_DIM + f;
            if (!hi) { mu[o] = aA; z[o] = aA + tlo; }
            else     { lv[o] = aA; }
        }
        if (hasB) {
            float t = expf(0.5f * aB) * eps[(size_t)vb * Z_DIM + f];
            float tlo = __shfl(t, lane | 32);
            size_t o = (size_t)vb * Z_DIM + f;
            if (!hi) { mu[o] = aB; z[o] = aB + tlo; }
            else     { lv[o] = aB; }
        }
    }
}

// ---------------------------------------------------------------------------
extern "C" void kernel_launch(void* const* d_in, const int* in_sizes, int n_in,
                              void* d_out, int out_size, void* d_ws, size_t ws_size,
                              hipStream_t stream) {
    const float* x   = (const float*)d_in[0];
    const void*  ei  = d_in[1];
    const float* W1  = (const float*)d_in[2];
    const float* b1  = (const float*)d_in[3];
    const float* W2  = (const float*)d_in[4];
    const float* b2  = (const float*)d_in[5];
    const float* Wmu = (const float*)d_in[6];
    const float* bmu = (const float*)d_in[7];
    const float* Wlv = (const float*)d_in[8];
    const float* blv = (const float*)d_in[9];
    const float* eps = (const float*)d_in[10];
    float* out = (float*)d_out;
    (void)in_sizes; (void)n_in; (void)out_size; (void)ws_size;

    char* ws = (char*)d_ws;
    size_t off = 0;
    auto alloc = [&](size_t bytes) -> void* {
        void* p = ws + off;
        off += (bytes + 255) & ~(size_t)255;
        return p;
    };
    int2*           ep     = (int2*)alloc(sizeof(int2) * N_EDGES);   // 6.4 MB
    int*            rowptr = (int*)alloc(sizeof(int) * (N_NODES + 1));
    int*            cursor = (int*)alloc(sizeof(int) * N_NODES);
    int*            cnt    = (int*)alloc(sizeof(int) * N_NODES);
    float*          dinv   = (float*)alloc(sizeof(float) * N_NODES);
    int*            flag   = (int*)alloc(sizeof(int) * 64);
    int*            bsum   = (int*)alloc(sizeof(int) * 256);
    unsigned short* xb     = (unsigned short*)alloc(sizeof(short) * (size_t)N_NODES * IN_DIM);  // 3.2 MB
    unsigned short* h1     = (unsigned short*)alloc(sizeof(short) * (size_t)N_NODES * HIDDEN);  // 6.4 MB
    unsigned short* h2     = (unsigned short*)alloc(sizeof(short) * (size_t)N_NODES * HIDDEN);  // 6.4 MB

    prep_kernel<<<(N_NODES * IN_DIM + 255) / 256, 256, 0, stream>>>(x, xb, (const int*)ei, flag, cnt);
    hist_kernel<<<(N_EDGES + 255) / 256, 256, 0, stream>>>(ei, flag, cnt);
    scan1_kernel<<<NB_SCAN, SCAN_B, 0, stream>>>(cnt, rowptr, bsum, dinv);
    scan2_kernel<<<1, 256, 0, stream>>>(bsum, NB_SCAN);
    scan3_kernel<<<NB_SCAN, SCAN_B, 0, stream>>>(rowptr, bsum, cursor);
    scatter_kernel<<<(N_EDGES + 255) / 256, 256, 0, stream>>>(ei, flag, dinv, cursor, ep);

    const int FB = 2048;   // 8192 waves
    fused_layer_kernel<IN_DIM><<<FB, 256, 0, stream>>>(rowptr, ep, dinv, xb, W1, b1, h1);
    fused_layer_kernel<HIDDEN><<<FB, 256, 0, stream>>>(rowptr, ep, dinv, h1, W2, b2, h2);
    fused_head_kernel<<<FB, 256, 0, stream>>>(rowptr, ep, dinv, h2,
                                              Wmu, bmu, Wlv, blv, eps, out);
}